// Round 15
// baseline (545.812 us; speedup 1.0000x reference)
//
#include <hip/hip_runtime.h>

#define NN 100000
#define NE 1600000
#define NG 1000
#define SLOT 48              // fixed slots/node; Poisson(16) max deg ~35 << 47
#define NGRP 8               // binning groups for scatter (srcs window 2.4MB < XCD L2)
#define NODES_PER_GRP 12500  // NN/NGRP
#define CSR_NB 256           // blocks per group for fused scatter

typedef _Float16 f16x8 __attribute__((ext_vector_type(8)));
typedef _Float16 f16x4 __attribute__((ext_vector_type(4)));
typedef _Float16 f16x2 __attribute__((ext_vector_type(2)));
typedef float f32x16 __attribute__((ext_vector_type(16)));
#define XROW 72  // xform LDS row stride (halves)

// ---------- h1 paired fp16 + fused att1 + cnt/self-loop init + self-loop ew1 ----------
__global__ void k_h1(const float* __restrict__ x, const float* __restrict__ ffw,
                     const float* __restrict__ ffb, const float* __restrict__ g1w,
                     const float* __restrict__ asw, const float* __restrict__ adw,
                     _Float16* __restrict__ h1p, float* __restrict__ asp,
                     float* __restrict__ ad_, int* __restrict__ cnt,
                     int* __restrict__ srcs, uint2* __restrict__ ew) {
    int tid = blockIdx.x * 256 + threadIdx.x;  // NN*64 exact
    if (tid < NN) {
        cnt[tid] = 1;                    // slot 0 = self-loop
        srcs[(size_t)tid * SLOT] = tid;
    }
    int n = __builtin_amdgcn_readfirstlane(tid >> 6);
    int jp = threadIdx.x & 63;
    float xv[4];
#pragma unroll
    for (int k = 0; k < 4; k++) xv[k] = x[n * 4 + k];
    float h0[8];
#pragma unroll
    for (int o = 0; o < 8; o++) {
        float a = ffb[o];
#pragma unroll
        for (int k = 0; k < 4; k++) a = fmaf(xv[k], ffw[o * 4 + k], a);
        h0[o] = a;
    }
    const float* w0 = g1w + jp * 8;
    const float* w1 = g1w + (jp + 64) * 8;
    float a0 = 0.f, a1 = 0.f;
#pragma unroll
    for (int k = 0; k < 8; k++) { a0 = fmaf(h0[k], w0[k], a0); a1 = fmaf(h0[k], w1[k], a1); }
    f16x2 r; r[0] = (_Float16)a0; r[1] = (_Float16)a1;
    *(f16x2*)(h1p + ((size_t)n * 64 + jp) * 2) = r;
    float p0 = a0 * asw[jp], p1 = a1 * asw[jp + 64];
    float d0 = a0 * adw[jp], d1 = a1 * adw[jp + 64];
#pragma unroll
    for (int m = 1; m <= 16; m <<= 1) {
        p0 += __shfl_xor(p0, m, 64); p1 += __shfl_xor(p1, m, 64);
        d0 += __shfl_xor(d0, m, 64); d1 += __shfl_xor(d1, m, 64);
    }
    if ((jp & 31) == 0) {
        int half = jp >> 5;
        *(float2*)(asp + n * 4 + half * 2) = make_float2(p0, p1);
        ad_[n * 4 + half] = d0;
        ad_[n * 4 + 2 + half] = d1;
        // self-loop edge weight for slot 0: lane0 -> heads{0,2} (.x), lane32 -> {1,3} (.y)
        float eA = p0 + d0; eA = fmaxf(eA, 0.2f * eA);
        float eB = p1 + d1; eB = fmaxf(eB, 0.2f * eB);
        union { unsigned u; _Float16 h[2]; } c;
        c.h[0] = (_Float16)__expf(eA); c.h[1] = (_Float16)__expf(eB);
        ((unsigned*)(ew + (size_t)n * SLOT))[half] = c.u;
    }
}

// ---------- FUSED: fixed-slot scatter WITH inline ew1 (k_ew1 deleted)
//            + prep (reads only input weights). ----------
#define APK_F1 24576
#define APK_F2 90112
#define APK_TOT 155648
__global__ void k_scatprep(const int* __restrict__ ei, int* __restrict__ cnt,
                           int* __restrict__ srcs, uint2* __restrict__ ew,
                           const float* __restrict__ asp, const float* __restrict__ ad1,
                           const float* __restrict__ enc_in_w, const float* __restrict__ enc_in_b,
                           const float* __restrict__ enc_out_w, const float* __restrict__ enc_out_b,
                           const float* __restrict__ sa_in_w, const float* __restrict__ sa_in_b,
                           const float* __restrict__ sa_out_w, const float* __restrict__ sa_out_b,
                           const float* __restrict__ ca_in_w, const float* __restrict__ ca_in_b,
                           const float* __restrict__ ca_out_w, const float* __restrict__ ca_out_b,
                           const float* __restrict__ ef1, const float* __restrict__ df1,
                           const float* __restrict__ ef2, const float* __restrict__ df2,
                           const float* __restrict__ g2w,
                           _Float16* __restrict__ apk, float* __restrict__ fb,
                           _Float16* __restrict__ apw2) {
    if (blockIdx.x < NGRP * CSR_NB) {  // ---- scatter part (8-wide MLP unroll) ----
        int g = blockIdx.x & (NGRP - 1);
        int bi = blockIdx.x >> 3;
        int lo = g * NODES_PER_GRP, hi = lo + NODES_PER_GRP;
        const int stride = CSR_NB * 256;
#define SLD(q) int ee##q = e + q * stride; int d##q = -1, s##q = 0; \
               if (ee##q < NE) { d##q = __builtin_nontemporal_load(ei + NE + ee##q); \
                                 s##q = __builtin_nontemporal_load(ei + ee##q); }
#define SAT(q) if (d##q >= lo && d##q < hi) { int p = atomicAdd(&cnt[d##q], 1); \
               if (p < SLOT) { \
                   srcs[(size_t)d##q * SLOT + p] = s##q; \
                   float4 a = *(const float4*)(asp + s##q * 4); \
                   float4 b = *(const float4*)(ad1 + d##q * 4); \
                   float e0 = a.x + b.x; e0 = fmaxf(e0, 0.2f * e0); \
                   float e2 = a.y + b.z; e2 = fmaxf(e2, 0.2f * e2); \
                   float e1 = a.z + b.y; e1 = fmaxf(e1, 0.2f * e1); \
                   float e3 = a.w + b.w; e3 = fmaxf(e3, 0.2f * e3); \
                   union { unsigned u; _Float16 h[2]; } c0, c1; \
                   c0.h[0] = (_Float16)__expf(e0); c0.h[1] = (_Float16)__expf(e2); \
                   c1.h[0] = (_Float16)__expf(e1); c1.h[1] = (_Float16)__expf(e3); \
                   uint2 o; o.x = c0.u; o.y = c1.u; \
                   ew[(size_t)d##q * SLOT + p] = o; } }
        for (int e = bi * 256 + threadIdx.x; e < NE; e += 8 * stride) {
            SLD(0) SLD(1) SLD(2) SLD(3) SLD(4) SLD(5) SLD(6) SLD(7)
            SAT(0) SAT(1) SAT(2) SAT(3) SAT(4) SAT(5) SAT(6) SAT(7)
        }
        return;
    }
    // ---- prep part ----
    int gt = (blockIdx.x - NGRP * CSR_NB) * 256 + threadIdx.x;  // 640*256 = 163840 exact
    if (gt < 24576) {  // attention-fold A-frags + fused bias
        int tid = gt;
        int p = tid >> 12, rr = tid & 4095, j = rr >> 6, k = rr & 63;
        int li = p & 1;
        const float *iw, *ib, *ow, *ob;
        if (p < 2)      { iw = enc_in_w + li * 12288; ib = enc_in_b + li * 192; ow = enc_out_w + li * 4096; ob = enc_out_b + li * 64; }
        else if (p < 4) { iw = sa_in_w + li * 12288;  ib = sa_in_b + li * 192;  ow = sa_out_w + li * 4096;  ob = sa_out_b + li * 64; }
        else            { iw = ca_in_w + li * 12288;  ib = ca_in_b + li * 192;  ow = ca_out_w + li * 4096;  ob = ca_out_b + li * 64; }
        float a = 0.f;
        for (int m = 0; m < 64; m++) a = fmaf(ow[j * 64 + m], iw[(128 + m) * 64 + k], a);
        int l = ((k >> 3) & 1) * 32 + (j & 31);
        apk[p * 4096 + (((j >> 5) * 4 + (k >> 4)) * 64 + l) * 8 + (k & 7)] = (_Float16)a;
        if (k == 0) {
            float fa = ob[j];
            for (int m = 0; m < 64; m++) fa = fmaf(ow[j * 64 + m], ib[128 + m], fa);
            fb[p * 64 + j] = fa;
        }
    } else {  // FFN/gat2 packs
        int tid = gt - 24576;
        if (tid < 65536) {
            int pl = tid >> 14, idx = tid & 16383;
            int mt = idx >> 11, ks = (idx >> 9) & 3, l = (idx >> 3) & 63, d = idx & 7;
            int m = mt * 32 + (l & 31), k = ks * 16 + (l >> 5) * 8 + d;
            const float* f1 = (pl < 2) ? ef1 + pl * 16384 : df1 + (pl - 2) * 16384;
            apk[APK_F1 + pl * 16384 + idx] = (_Float16)f1[m * 64 + k];
        } else if (tid < 131072) {
            int rr = tid - 65536;
            int pl = rr >> 14, idx = rr & 16383;
            int mt = idx >> 13, ks = (idx >> 9) & 15, l = (idx >> 3) & 63, d = idx & 7;
            int m = mt * 32 + (l & 31), k = ks * 16 + (l >> 5) * 8 + d;
            const float* f2 = (pl < 2) ? ef2 + pl * 16384 : df2 + (pl - 2) * 16384;
            apk[APK_F2 + pl * 16384 + idx] = (_Float16)f2[m * 256 + k];
        } else {
            int rr = tid - 131072;
            int mtks = rr >> 9, l = (rr >> 3) & 63, d = rr & 7;
            int mt = mtks >> 3, ks = mtks & 7;
            int m = mt * 32 + (l & 31), k = ks * 16 + (l >> 5) * 8 + d;
            apw2[rr] = (_Float16)g2w[m * 128 + k];
        }
    }
}

// ---------- per-edge softmax weights, layer 2 (natural head order), fixed-slot ----------
__global__ void k_ew2(const int* __restrict__ cnt, const int* __restrict__ srcs,
                      const float* __restrict__ as_, const float* __restrict__ ad_,
                      uint2* __restrict__ ew) {
    int t = blockIdx.x * 256 + threadIdx.x;
    int d = t >> 4, li = t & 15;
    if (d >= NN) return;
    size_t off = (size_t)d * SLOT;
    int deg = cnt[d]; if (deg > SLOT) deg = SLOT;
    float4 b = *(const float4*)(ad_ + d * 4);
    for (int j = li; j < deg; j += 16) {
        int s = srcs[off + j];
        float4 a = *(const float4*)(as_ + s * 4);
        float e0 = a.x + b.x; e0 = fmaxf(e0, 0.2f * e0);
        float e1 = a.y + b.y; e1 = fmaxf(e1, 0.2f * e1);
        float e2 = a.z + b.z; e2 = fmaxf(e2, 0.2f * e2);
        float e3 = a.w + b.w; e3 = fmaxf(e3, 0.2f * e3);
        union { unsigned u; _Float16 h[2]; } c0, c1;
        c0.h[0] = (_Float16)__expf(e0); c0.h[1] = (_Float16)__expf(e1);
        c1.h[0] = (_Float16)__expf(e2); c1.h[1] = (_Float16)__expf(e3);
        uint2 o; o.x = c0.u; o.y = c1.u;
        ew[off + j] = o;
    }
}

// ---------- GAT layer 1: scalar-pipe srcs/ew, 8-wide NAMED-SCALAR gather unroll ----------
#define G1LD(q)  int s##q = sp[j + q]; uint2 e##q = wp[j + q];
#define G1LDM(q) int jj##q = j + q; int jc##q = jj##q < deg ? jj##q : deg - 1; \
                 int s##q = sp[jc##q]; uint2 e##q = wp[jc##q]; \
                 if (jj##q >= deg) { e##q.x = 0u; e##q.y = 0u; }
#define G1GA(q)  f16x2 p##q = *(const f16x2*)(h1p + (size_t)s##q * 128 + lane * 2);
#define G1AC(q, W0, W1, A0, A1) { \
    union { unsigned u; _Float16 h[2]; } c; c.u = hA ? e##q.y : e##q.x; \
    float w0 = (float)c.h[0], w1 = (float)c.h[1]; \
    W0 += w0; W1 += w1; \
    A0 = fmaf(w0, (float)p##q[0], A0); A1 = fmaf(w1, (float)p##q[1], A1); }

__global__ void k_gat1(const int* __restrict__ cnt, const int* __restrict__ srcs,
                       const uint2* __restrict__ ew, const _Float16* __restrict__ h1p,
                       const float* __restrict__ bias, _Float16* __restrict__ g1h) {
    int wid = __builtin_amdgcn_readfirstlane((blockIdx.x * 256 + threadIdx.x) >> 6);
    int lane = threadIdx.x & 63;
    if (wid >= NN) return;
    int deg = cnt[wid]; if (deg > SLOT) deg = SLOT;
    int hA = lane >> 5;
    const int* sp = srcs + (size_t)wid * SLOT;
    const uint2* wp = ew + (size_t)wid * SLOT;
    float ws0 = 0.f, ws1 = 0.f, ac0 = 0.f, ac1 = 0.f;
    float ws0b = 0.f, ws1b = 0.f, ac0b = 0.f, ac1b = 0.f;
    int j = 0;
    for (; j + 8 <= deg; j += 8) {
        G1LD(0) G1LD(1) G1LD(2) G1LD(3) G1LD(4) G1LD(5) G1LD(6) G1LD(7)
        G1GA(0) G1GA(1) G1GA(2) G1GA(3) G1GA(4) G1GA(5) G1GA(6) G1GA(7)
        G1AC(0, ws0, ws1, ac0, ac1)     G1AC(1, ws0b, ws1b, ac0b, ac1b)
        G1AC(2, ws0, ws1, ac0, ac1)     G1AC(3, ws0b, ws1b, ac0b, ac1b)
        G1AC(4, ws0, ws1, ac0, ac1)     G1AC(5, ws0b, ws1b, ac0b, ac1b)
        G1AC(6, ws0, ws1, ac0, ac1)     G1AC(7, ws0b, ws1b, ac0b, ac1b)
    }
    if (j < deg) {
        G1LDM(0) G1LDM(1) G1LDM(2) G1LDM(3) G1LDM(4) G1LDM(5) G1LDM(6) G1LDM(7)
        G1GA(0) G1GA(1) G1GA(2) G1GA(3) G1GA(4) G1GA(5) G1GA(6) G1GA(7)
        G1AC(0, ws0, ws1, ac0, ac1)     G1AC(1, ws0b, ws1b, ac0b, ac1b)
        G1AC(2, ws0, ws1, ac0, ac1)     G1AC(3, ws0b, ws1b, ac0b, ac1b)
        G1AC(4, ws0, ws1, ac0, ac1)     G1AC(5, ws0b, ws1b, ac0b, ac1b)
        G1AC(6, ws0, ws1, ac0, ac1)     G1AC(7, ws0b, ws1b, ac0b, ac1b)
    }
    ws0 += ws0b; ws1 += ws1b; ac0 += ac0b; ac1 += ac1b;
    float v0 = ac0 / ws0 + bias[lane];      v0 = fmaxf(v0, 0.01f * v0);
    float v1 = ac1 / ws1 + bias[lane + 64]; v1 = fmaxf(v1, 0.01f * v1);
    g1h[(size_t)wid * 128 + lane] = (_Float16)v0;
    g1h[(size_t)wid * 128 + lane + 64] = (_Float16)v1;
}

// ---------- GAT layer 2, fixed-slot ----------
#define G2LD(q)  int s##q = sp[j + q]; uint2 e##q = wp[j + q];
#define G2LDM(q) int jj##q = j + q; int jc##q = jj##q < deg ? jj##q : deg - 1; \
                 int s##q = sp[jc##q]; uint2 e##q = wp[jc##q]; \
                 if (jj##q >= deg) { e##q.x = 0u; e##q.y = 0u; }
#define G2GA(q)  float hv##q = (float)h2h[(size_t)s##q * 64 + lane];
#define G2AC(q, W, A) { \
    unsigned sel = (hd & 2) ? e##q.y : e##q.x; \
    union { unsigned u; _Float16 h[2]; } c; c.u = sel >> sh; \
    float w = (float)c.h[0]; W += w; A = fmaf(w, hv##q, A); }

__global__ void k_gat2(const int* __restrict__ cnt, const int* __restrict__ srcs,
                       const uint2* __restrict__ ew, const _Float16* __restrict__ h2h,
                       const float* __restrict__ bias, _Float16* __restrict__ g2h) {
    int wid = __builtin_amdgcn_readfirstlane((blockIdx.x * 256 + threadIdx.x) >> 6);
    int lane = threadIdx.x & 63;
    if (wid >= NN) return;
    int deg = cnt[wid]; if (deg > SLOT) deg = SLOT;
    int hd = lane >> 4;
    int sh = (hd & 1) * 16;
    const int* sp = srcs + (size_t)wid * SLOT;
    const uint2* wp = ew + (size_t)wid * SLOT;
    float ws = 0.f, ac = 0.f, wsb = 0.f, acb = 0.f;
    int j = 0;
    for (; j + 8 <= deg; j += 8) {
        G2LD(0) G2LD(1) G2LD(2) G2LD(3) G2LD(4) G2LD(5) G2LD(6) G2LD(7)
        G2GA(0) G2GA(1) G2GA(2) G2GA(3) G2GA(4) G2GA(5) G2GA(6) G2GA(7)
        G2AC(0, ws, ac)  G2AC(1, wsb, acb)
        G2AC(2, ws, ac)  G2AC(3, wsb, acb)
        G2AC(4, ws, ac)  G2AC(5, wsb, acb)
        G2AC(6, ws, ac)  G2AC(7, wsb, acb)
    }
    if (j < deg) {
        G2LDM(0) G2LDM(1) G2LDM(2) G2LDM(3) G2LDM(4) G2LDM(5) G2LDM(6) G2LDM(7)
        G2GA(0) G2GA(1) G2GA(2) G2GA(3) G2GA(4) G2GA(5) G2GA(6) G2GA(7)
        G2AC(0, ws, ac)  G2AC(1, wsb, acb)
        G2AC(2, ws, ac)  G2AC(3, wsb, acb)
        G2AC(4, ws, ac)  G2AC(5, wsb, acb)
        G2AC(6, ws, ac)  G2AC(7, wsb, acb)
    }
    ws += wsb; ac += acb;
    float v = ac / ws + bias[lane]; v = fmaxf(v, 0.01f * v);
    g2h[(size_t)wid * 64 + lane] = (_Float16)v;
}

// ---------- h2 = g1h @ gat2_w.T via MFMA + fused att2 coeffs ----------
#define GROW 136
#define CROW 72
__global__ __launch_bounds__(256, 2) void k_h2m(const _Float16* __restrict__ g1h,
                                                const _Float16* __restrict__ apw2,
                                                const float* __restrict__ asw,
                                                const float* __restrict__ adw,
                                                _Float16* __restrict__ h2h,
                                                float* __restrict__ as_,
                                                float* __restrict__ ad_) {
    __shared__ _Float16 ls[4 * 32 * GROW];
    const int t = threadIdx.x;
    const int w = t >> 6, l = t & 63;
    const int col = l & 31, hf = l >> 5;
    const int wv = blockIdx.x * 4 + w;
    const int nb = wv * 32;
    if (nb >= NN) return;
    _Float16* g16 = ls + w * (32 * GROW);
    const int r = l >> 1, hb = l & 1;
    {
        int nr = nb + r; if (nr >= NN) nr = NN - 1;
        const _Float16* src = g1h + (size_t)nr * 128 + hb * 64;
        _Float16* dst = g16 + r * GROW + hb * 64;
#pragma unroll
        for (int q = 0; q < 8; q++)
            *(f16x8*)(dst + q * 8) = *(const f16x8*)(src + q * 8);
    }
    f16x8 bf[8];
#pragma unroll
    for (int ks = 0; ks < 8; ks++)
        bf[ks] = *(const f16x8*)(g16 + col * GROW + ks * 16 + hf * 8);
    f32x16 acc0, acc1;
#pragma unroll
    for (int i = 0; i < 16; i++) { acc0[i] = 0.f; acc1[i] = 0.f; }
#pragma unroll
    for (int ks = 0; ks < 8; ks++) {
        f16x8 a0 = *(const f16x8*)(apw2 + ((0 * 8 + ks) * 64 + l) * 8);
        f16x8 a1 = *(const f16x8*)(apw2 + ((1 * 8 + ks) * 64 + l) * 8);
        acc0 = __builtin_amdgcn_mfma_f32_32x32x16_f16(a0, bf[ks], acc0, 0, 0, 0);
        acc1 = __builtin_amdgcn_mfma_f32_32x32x16_f16(a1, bf[ks], acc1, 0, 0, 0);
    }
    // fused att2: per-head dots on f16-rounded values (identical to reading h2h back)
    {
        float pa0 = 0.f, pa1 = 0.f, pa2 = 0.f, pa3 = 0.f;
        float pd0 = 0.f, pd1 = 0.f, pd2 = 0.f, pd3 = 0.f;
#pragma unroll
        for (int rg = 0; rg < 4; rg++)
#pragma unroll
            for (int i = 0; i < 4; i++) {
                int rr = rg * 4 + i;
                int f = i + rg * 8 + hf * 4;      // feature row in [0,32)
                float h0v = (float)(_Float16)acc0[rr];
                float h1v = (float)(_Float16)acc1[rr];
                float s0 = asw[f], d0v = adw[f];
                float s1 = asw[32 + f], d1v = adw[32 + f];
                if (rg < 2) { pa0 = fmaf(h0v, s0, pa0); pd0 = fmaf(h0v, d0v, pd0);
                              pa2 = fmaf(h1v, s1, pa2); pd2 = fmaf(h1v, d1v, pd2); }
                else        { pa1 = fmaf(h0v, s0, pa1); pd1 = fmaf(h0v, d0v, pd1);
                              pa3 = fmaf(h1v, s1, pa3); pd3 = fmaf(h1v, d1v, pd3); }
            }
        pa0 += __shfl_xor(pa0, 32, 64); pa1 += __shfl_xor(pa1, 32, 64);
        pa2 += __shfl_xor(pa2, 32, 64); pa3 += __shfl_xor(pa3, 32, 64);
        pd0 += __shfl_xor(pd0, 32, 64); pd1 += __shfl_xor(pd1, 32, 64);
        pd2 += __shfl_xor(pd2, 32, 64); pd3 += __shfl_xor(pd3, 32, 64);
        if (hf == 0 && nb + col < NN) {
            *(float4*)(as_ + (size_t)(nb + col) * 4) = make_float4(pa0, pa1, pa2, pa3);
            *(float4*)(ad_ + (size_t)(nb + col) * 4) = make_float4(pd0, pd1, pd2, pd3);
        }
    }
    _Float16* c16 = g16;
#pragma unroll
    for (int rg = 0; rg < 4; rg++) {
        f16x4 h0, h1;
#pragma unroll
        for (int i = 0; i < 4; i++) { h0[i] = (_Float16)acc0[rg * 4 + i]; h1[i] = (_Float16)acc1[rg * 4 + i]; }
        *(f16x4*)(c16 + col * CROW + rg * 8 + hf * 4) = h0;
        *(f16x4*)(c16 + col * CROW + 32 + rg * 8 + hf * 4) = h1;
    }
    if (nb + r < NN) {
        _Float16* dst = h2h + (size_t)(nb + r) * 64 + hb * 32;
        const _Float16* srow = c16 + r * CROW + hb * 32;
#pragma unroll
        for (int q = 0; q < 4; q++)
            *(f16x8*)(dst + q * 8) = *(const f16x8*)(srow + q * 8);
    }
}

// ---------- MFMA transformer: round-3 shape (4x64 waves, 2-barrier LDS staging) ----------
struct XQ {
    const _Float16* apk; const float* fb;
    const float* ef1b; const float* ef2b; const float* df1b; const float* df2b;
    const float* el1g; const float* el1b; const float* el2g; const float* el2b;
    const float* dl1g; const float* dl1b; const float* dl2g; const float* dl2b;
    const float* dl3g; const float* dl3b;
};

__device__ __forceinline__ void xstore(_Float16* xw, const float y[4][16], int col, int hf) {
#pragma unroll
    for (int nt = 0; nt < 2; nt++)
#pragma unroll
        for (int mt = 0; mt < 2; mt++)
#pragma unroll
            for (int rg = 0; rg < 4; rg++) {
                f16x4 h4;
#pragma unroll
                for (int i = 0; i < 4; i++) h4[i] = (_Float16)y[mt * 2 + nt][rg * 4 + i];
                *(f16x4*)(xw + (nt * 32 + col) * XROW + mt * 32 + rg * 8 + hf * 4) = h4;
            }
}

__device__ __forceinline__ void loadbf(const _Float16* xw, f16x8 bf[2][4], int col, int hf) {
#pragma unroll
    for (int nt = 0; nt < 2; nt++)
#pragma unroll
        for (int ks = 0; ks < 4; ks++)
            bf[nt][ks] = *(const f16x8*)(xw + (nt * 32 + col) * XROW + ks * 16 + hf * 8);
}

__device__ __forceinline__ void lnw(float y[4][16], const float* g, const float* b, int hf) {
#pragma unroll
    for (int nt = 0; nt < 2; nt++) {
        float s = 0.f, q = 0.f;
#pragma unroll
        for (int mt = 0; mt < 2; mt++)
#pragma unroll
            for (int r = 0; r < 16; r++) { float v = y[mt * 2 + nt][r]; s += v; q = fmaf(v, v, q); }
        s += __shfl_xor(s, 32, 64);
        q += __shfl_xor(q, 32, 64);
        float m = s * 0.015625f;
        float var = fmaf(q, 0.015625f, -m * m);
        float rs = rsqrtf(var + 1e-5f);
#pragma unroll
        for (int mt = 0; mt < 2; mt++)
#pragma unroll
            for (int rg = 0; rg < 4; rg++) {
                float4 g4 = *(const float4*)(g + mt * 32 + rg * 8 + hf * 4);
                float4 b4 = *(const float4*)(b + mt * 32 + rg * 8 + hf * 4);
                float* yp = &y[mt * 2 + nt][rg * 4];
                yp[0] = fmaf((yp[0] - m) * rs, g4.x, b4.x);
                yp[1] = fmaf((yp[1] - m) * rs, g4.y, b4.y);
                yp[2] = fmaf((yp[2] - m) * rs, g4.z, b4.z);
                yp[3] = fmaf((yp[3] - m) * rs, g4.w, b4.w);
            }
    }
}

__global__ __launch_bounds__(256, 2) void k_xform(const _Float16* __restrict__ yin,
                                                  float* __restrict__ yout, XQ P) {
    __shared__ _Float16 xs[4 * 64 * XROW];
    __shared__ _Float16 wb[8192];
    const int t = threadIdx.x;
    const int w = t >> 6, l = t & 63;
    const int col = l & 31, hf = l >> 5;
    _Float16* xw = xs + w * (64 * XROW);
    const int nb = blockIdx.x * 256 + w * 64;
    const int nn0 = nb + col, nn1 = nb + 32 + col;
    const int nc0 = nn0 < NN ? nn0 : NN - 1;
    const int nc1 = nn1 < NN ? nn1 : NN - 1;

    float y[4][16];
#pragma unroll
    for (int mt = 0; mt < 2; mt++)
#pragma unroll
        for (int nt = 0; nt < 2; nt++) {
            const _Float16* src = yin + (size_t)(nt ? nc1 : nc0) * 64 + mt * 32 + hf * 4;
#pragma unroll
            for (int rg = 0; rg < 4; rg++) {
                f16x4 v = *(const f16x4*)(src + rg * 8);
#pragma unroll
                for (int i = 0; i < 4; i++) y[mt * 2 + nt][rg * 4 + i] = (float)v[i];
            }
        }
    f16x8 bf[2][4];
    xstore(xw, y, col, hf);
    loadbf(xw, bf, col, hf);

#pragma unroll 1
    for (int layer = 0; layer < 4; layer++) {
        const bool enc = layer < 2;
        const int li = enc ? layer : layer - 2;
        const int nat = enc ? 1 : 2;
#pragma unroll 1
        for (int at = 0; at < nat; at++) {
            const int p = enc ? layer : (at == 0 ? 2 + li : 4 + li);
            const _Float16* apA = P.apk + p * 4096;
            __syncthreads();
#pragma unroll
            for (int i = 0; i < 2; i++)
                *(f16x8*)(wb + (t + i * 256) * 8) = *(const f16x8*)(apA + (t + i * 256) * 8);
            __syncthreads();
            const float* fbp = P.fb + p * 64;
            f32x16 acc[4];
#pragma unroll
            for (int mt = 0; mt < 2; mt++) {
                f32x16 a;
#pragma unroll
                for (int rg = 0; rg < 4; rg++) {
                    float4 b4 = *(const float4*)(fbp + mt * 32 + rg * 8 + hf * 4);
                    a[rg * 4 + 0] = b4.x; a[rg * 4 + 1] = b4.y; a[rg * 4 + 2] = b4.z; a[rg * 4 + 3] = b4.w;
                }
                acc[mt * 2 + 0] = a; acc[mt * 2 + 1] = a;
            }
#pragma unroll
            for (int mt = 0; mt < 2; mt++)
#pragma unroll
                for (int ks = 0; ks < 4; ks++) {
                    f16x8 af = *(const f16x8*)(wb + ((mt * 4 + ks) * 64 + l) * 8);
                    acc[mt * 2 + 0] = __builtin_amdgcn_mfma_f32_32x32x16_f16(af, bf[0][ks], acc[mt * 2 + 0], 0, 0, 0);
                    acc[mt * 2 + 1] = __builtin_amdgcn_mfma_f32_32x32x16_f16(af, bf[1][ks], acc[mt * 2 + 1], 0, 0, 0);
                }
#pragma unroll
            for (int ti = 0; ti < 4; ti++)
#pragma unroll
                for (int r = 0; r < 16; r++) y[ti][r] += acc[ti][r];
            const float *g, *b;
            if (enc)          { g = P.el1g + li * 64; b = P.el1b + li * 64; }
            else if (at == 0) { g = P.dl1g + li * 64; b = P.dl1b + li * 64; }
            else              { g = P.dl2g + li * 64; b = P.dl2b + li * 64; }
            lnw(y, g, b, hf);
            xstore(xw, y, col, hf);
            loadbf(xw, bf, col, hf);
        }
        const int pl = enc ? layer : 2 + li;
        const _Float16* apF1 = P.apk + APK_F1 + pl * 16384;
        const _Float16* apF2 = P.apk + APK_F2 + pl * 16384;
        const float* f1bp = (enc ? P.ef1b : P.df1b) + li * 256;
        const float* f2bp = (enc ? P.ef2b : P.df2b) + li * 64;
        f32x16 out[4];
#pragma unroll
        for (int mt = 0; mt < 2; mt++) {
            f32x16 a;
#pragma unroll
            for (int rg = 0; rg < 4; rg++) {
                float4 b4 = *(const float4*)(f2bp + mt * 32 + rg * 8 + hf * 4);
                a[rg * 4 + 0] = b4.x; a[rg * 4 + 1] = b4.y; a[rg * 4 + 2] = b4.z; a[rg * 4 + 3] = b4.w;
            }
            out[mt * 2 + 0] = a; out[mt * 2 + 1] = a;
        }
#pragma unroll 1
        for (int c = 0; c < 4; c++) {
            __syncthreads();
#pragma unroll
            for (int i = 0; i < 2; i++)
                *(f16x8*)(wb + (t + i * 256) * 8) = *(const f16x8*)(apF1 + c * 4096 + (t + i * 256) * 8);
            *(f16x8*)(wb + 4096 + t * 8) = *(const f16x8*)(apF2 + c * 2048 + t * 8);
            *(f16x8*)(wb + 6144 + t * 8) = *(const f16x8*)(apF2 + 8192 + c * 2048 + t * 8);
            __syncthreads();
            f32x16 ha[4];
#pragma unroll
            for (int hmt = 0; hmt < 2; hmt++) {
                f32x16 a;
#pragma unroll
                for (int rg = 0; rg < 4; rg++) {
                    float4 b4 = *(const float4*)(f1bp + c * 64 + hmt * 32 + rg * 8 + hf * 4);
                    a[rg * 4 + 0] = b4.x; a[rg * 4 + 1] = b4.y; a[rg * 4 + 2] = b4.z; a[rg * 4 + 3] = b4.w;
                }
                ha[hmt * 2 + 0] = a; ha[hmt * 2 + 1] = a;
            }
#pragma unroll
            for (int hmt = 0; hmt < 2; hmt++)
#pragma unroll
                for (int ks = 0; ks < 4; ks++) {
                    f16x8 af = *(const f16x8*)(wb + ((hmt * 4 + ks) * 64 + l) * 8);
                    ha[hmt * 2 + 0] = __builtin_amdgcn_mfma_f32_32x32x16_f16(af, bf[0][ks], ha[hmt * 2 + 0], 0, 0, 0);
                    ha[hmt * 2 + 1] = __builtin_amdgcn_mfma_f32_32x32x16_f16(af, bf[1][ks], ha[hmt * 2 + 1], 0, 0, 0);
                }
#pragma unroll
            for (int nt = 0; nt < 2; nt++)
#pragma unroll
                for (int hmt = 0; hmt < 2; hmt++)
#pragma unroll
                    for (int rg = 0; rg < 4; rg++) {
                        f16x4 h4;
#pragma unroll
                        for (int i = 0; i < 4; i++)
                            h4[i] = (_Float16)fmaxf(ha[hmt * 2 + nt][rg * 4 + i], 0.f);
                        *(f16x4*)(xw + (nt * 32 + col) * XROW + hmt * 32 + rg * 8 + hf * 4) = h4;
                    }
#pragma unroll
            for (int ksl = 0; ksl < 4; ksl++) {
                f16x8 hbf0 = *(const f16x8*)(xw + col * XROW + ksl * 16 + hf * 8);
                f16x8 hbf1 = *(const f16x8*)(xw + (32 + col) * XROW + ksl * 16 + hf * 8);
#pragma unroll
                for (int mt = 0; mt < 2; mt++) {
                    f16x8 af = *(const f16x8*)(wb + 4096 + mt * 2048 + (ksl * 64 + l) * 8);
                    out[mt * 2 + 0] = __builtin_amdgcn_mfma_f32_32x32x16_f16(af, hbf0, out[mt * 2 + 0], 0, 0, 0);
                    out[mt * 2 + 1] = __builtin_amdgcn_mfma_f32_32x32x16_f16(af, hbf1, out[mt * 2 + 1], 0, 0, 0);
                }
            }
        }
#pragma unroll
        for (int ti = 0; ti < 4; ti++)
#pragma unroll
            for (int r = 0; r < 16; r++) y[ti][r] += out[ti][r];
        const float* g2 = (enc ? P.el2g : P.dl3g) + li * 64;
        const float* b2 = (enc ? P.el2b : P.dl3b) + li * 64;
        lnw(y, g2, b2, hf);
        if (layer < 3) {
            xstore(xw, y, col, hf);
            loadbf(xw, bf, col, hf);
        }
    }
#pragma unroll
    for (int mt = 0; mt < 2; mt++)
#pragma unroll
        for (int nt = 0; nt < 2; nt++) {
            int n = nt ? nn1 : nn0;
            if (n < NN) {
                float* dst = yout + (size_t)n * 64 + mt * 32 + hf * 4;
#pragma unroll
                for (int rg = 0; rg < 4; rg++) {
                    const float* yp = &y[mt * 2 + nt][rg * 4];
                    *(float4*)(dst + rg * 8) = make_float4(yp[0], yp[1], yp[2], yp[3]);
                }
            }
        }
}

// ---------- global mean pool + fused final fc ----------
__global__ void k_pool(const float* __restrict__ y, const int* __restrict__ batch,
                       const float* __restrict__ fcw, const float* __restrict__ fcb,
                       float* __restrict__ out) {
    int b = blockIdx.x;
    int t = threadIdx.x;
    int ch = t & 63, r = t >> 6;
    int lo = 0, hi = NN;
    while (lo < hi) { int mid = (lo + hi) >> 1; if (batch[mid] < b) lo = mid + 1; else hi = mid; }
    int st = lo;
    hi = NN;
    while (lo < hi) { int mid = (lo + hi) >> 1; if (batch[mid] < b + 1) lo = mid + 1; else hi = mid; }
    int en = lo;
    float s = 0.f;
    for (int i = st + r; i < en; i += 4) s += y[(size_t)i * 64 + ch];
    __shared__ float red[256];
    __shared__ float pl[64];
    red[t] = s;
    __syncthreads();
    if (t < 64) {
        float tot = red[t] + red[t + 64] + red[t + 128] + red[t + 192];
        int cnt = en - st; if (cnt < 1) cnt = 1;
        pl[t] = tot / (float)cnt;
    }
    __syncthreads();
    if (t < 33) {
        const float* wv = fcw + t * 64;
        float a0 = 0.f, a1 = 0.f, a2 = 0.f, a3 = 0.f;
#pragma unroll
        for (int k = 0; k < 16; k++) {
            a0 = fmaf(pl[4 * k], wv[4 * k], a0);
            a1 = fmaf(pl[4 * k + 1], wv[4 * k + 1], a1);
            a2 = fmaf(pl[4 * k + 2], wv[4 * k + 2], a2);
            a3 = fmaf(pl[4 * k + 3], wv[4 * k + 3], a3);
        }
        out[b * 33 + t] = fcb[t] + (a0 + a1) + (a2 + a3);
    }
}

extern "C" void kernel_launch(void* const* d_in, const int* in_sizes, int n_in,
                              void* d_out, int out_size, void* d_ws, size_t ws_size,
                              hipStream_t stream) {
    (void)in_sizes; (void)n_in; (void)out_size; (void)ws_size;
    char* ws = (char*)d_ws;
    size_t o = 0;
    auto A = [&](size_t b) { size_t r = o; o += (b + 255) & ~(size_t)255; return r; };
    _Float16* h1p = (_Float16*)(ws + A((size_t)NN * 128 * 2));
    _Float16* h2h = (_Float16*)(ws + A((size_t)NN * 64 * 2));
    _Float16* g1h = (_Float16*)(ws + A((size_t)NN * 128 * 2));
    _Float16* g2h = (_Float16*)(ws + A((size_t)NN * 64 * 2));
    float* f_y   = (float*)(ws + A((size_t)NN * 64 * 4));
    float* f_asp = (float*)(ws + A((size_t)NN * 4 * 4));
    float* f_ad1 = (float*)(ws + A((size_t)NN * 4 * 4));
    float* f_as2 = (float*)(ws + A((size_t)NN * 4 * 4));
    float* f_ad2 = (float*)(ws + A((size_t)NN * 4 * 4));
    int* i_cnt   = (int*)(ws + A((size_t)NN * 4));
    int* i_srcs  = (int*)(ws + A((size_t)NN * SLOT * 4));
    uint2* e_w   = (uint2*)(ws + A((size_t)NN * SLOT * 8));
    float* f_fb  = (float*)(ws + A((size_t)6 * 64 * 4));
    _Float16* f_apk = (_Float16*)(ws + A((size_t)APK_TOT * 2));
    _Float16* apw2  = (_Float16*)(ws + A((size_t)8192 * 2));

    const float* x   = (const float*)d_in[0];
    const int* ei    = (const int*)d_in[1];
    const int* batch = (const int*)d_in[2];
    #define F32(i) ((const float*)d_in[i])

    k_h1<<<NN * 64 / 256, 256, 0, stream>>>(x, F32(3), F32(4), F32(5), F32(6), F32(7),
                                            h1p, f_asp, f_ad1, i_cnt, i_srcs, e_w);
    k_scatprep<<<NGRP * CSR_NB + 640, 256, 0, stream>>>(
        ei, i_cnt, i_srcs, e_w, f_asp, f_ad1,
        F32(13), F32(14), F32(15), F32(16),
        F32(25), F32(26), F32(27), F32(28),
        F32(29), F32(30), F32(31), F32(32),
        F32(17), F32(33), F32(19), F32(35), F32(9),
        f_apk, f_fb, apw2);
    k_gat1<<<NN * 64 / 256, 256, 0, stream>>>(i_cnt, i_srcs, e_w, h1p, F32(8), g1h);
    k_h2m<<<(NN / 32 + 3) / 4, 256, 0, stream>>>(g1h, apw2, F32(10), F32(11), h2h, f_as2, f_ad2);
    k_ew2<<<NN * 16 / 256, 256, 0, stream>>>(i_cnt, i_srcs, f_as2, f_ad2, e_w);
    k_gat2<<<NN * 64 / 256, 256, 0, stream>>>(i_cnt, i_srcs, e_w, h2h, F32(12), g2h);
    XQ Q;
    Q.apk = f_apk; Q.fb = f_fb;
    Q.ef1b = F32(18); Q.ef2b = F32(20);
    Q.df1b = F32(34); Q.df2b = F32(36);
    Q.el1g = F32(21); Q.el1b = F32(22); Q.el2g = F32(23); Q.el2b = F32(24);
    Q.dl1g = F32(37); Q.dl1b = F32(38); Q.dl2g = F32(39); Q.dl2b = F32(40);
    Q.dl3g = F32(41); Q.dl3b = F32(42);
    k_xform<<<(NN + 255) / 256, 256, 0, stream>>>(g2h, f_y, Q);
    k_pool<<<NG, 256, 0, stream>>>(f_y, batch, F32(43), F32(44), (float*)d_out);
    #undef F32
}

// Round 17
// 492.926 us; speedup vs baseline: 1.1073x; 1.1073x over previous
//
#include <hip/hip_runtime.h>

#define NN 100000
#define NE 1600000
#define NG 1000
#define SLOT 48              // fixed slots/node; Poisson(16) max deg ~35 << 47
#define NGRP 8               // binning groups for scatter (srcs window 2.4MB < XCD L2)
#define NODES_PER_GRP 12500  // NN/NGRP
#define CSR_NB 256           // blocks per group for fused scatter

typedef _Float16 f16x8 __attribute__((ext_vector_type(8)));
typedef _Float16 f16x4 __attribute__((ext_vector_type(4)));
typedef _Float16 f16x2 __attribute__((ext_vector_type(2)));
typedef float f32x16 __attribute__((ext_vector_type(16)));
#define XROW 72  // xform LDS row stride (halves)

// ---------- h1 paired fp16 + fused att1 + cnt/self-loop init (count kernel DELETED) ----------
__global__ void k_h1(const float* __restrict__ x, const float* __restrict__ ffw,
                     const float* __restrict__ ffb, const float* __restrict__ g1w,
                     const float* __restrict__ asw, const float* __restrict__ adw,
                     _Float16* __restrict__ h1p, float* __restrict__ asp,
                     float* __restrict__ ad_, int* __restrict__ cnt,
                     int* __restrict__ srcs) {
    int tid = blockIdx.x * 256 + threadIdx.x;  // NN*64 exact
    if (tid < NN) {
        cnt[tid] = 1;                    // slot 0 = self-loop
        srcs[(size_t)tid * SLOT] = tid;
    }
    int n = __builtin_amdgcn_readfirstlane(tid >> 6);
    int jp = threadIdx.x & 63;
    float xv[4];
#pragma unroll
    for (int k = 0; k < 4; k++) xv[k] = x[n * 4 + k];
    float h0[8];
#pragma unroll
    for (int o = 0; o < 8; o++) {
        float a = ffb[o];
#pragma unroll
        for (int k = 0; k < 4; k++) a = fmaf(xv[k], ffw[o * 4 + k], a);
        h0[o] = a;
    }
    const float* w0 = g1w + jp * 8;
    const float* w1 = g1w + (jp + 64) * 8;
    float a0 = 0.f, a1 = 0.f;
#pragma unroll
    for (int k = 0; k < 8; k++) { a0 = fmaf(h0[k], w0[k], a0); a1 = fmaf(h0[k], w1[k], a1); }
    f16x2 r; r[0] = (_Float16)a0; r[1] = (_Float16)a1;
    *(f16x2*)(h1p + ((size_t)n * 64 + jp) * 2) = r;
    float p0 = a0 * asw[jp], p1 = a1 * asw[jp + 64];
    float d0 = a0 * adw[jp], d1 = a1 * adw[jp + 64];
#pragma unroll
    for (int m = 1; m <= 16; m <<= 1) {
        p0 += __shfl_xor(p0, m, 64); p1 += __shfl_xor(p1, m, 64);
        d0 += __shfl_xor(d0, m, 64); d1 += __shfl_xor(d1, m, 64);
    }
    if ((jp & 31) == 0) {
        int half = jp >> 5;
        *(float2*)(asp + n * 4 + half * 2) = make_float2(p0, p1);
        ad_[n * 4 + half] = d0;
        ad_[n * 4 + 2 + half] = d1;
    }
}

// ---------- FUSED: fixed-slot scatter (blocks 0..2047, grid-stride, first)
//            + prep (blocks 2048..; reads only input weights). ----------
#define APK_F1 24576
#define APK_F2 90112
#define APK_TOT 155648
__global__ void k_scatprep(const int* __restrict__ ei, int* __restrict__ cnt,
                           int* __restrict__ srcs,
                           const float* __restrict__ enc_in_w, const float* __restrict__ enc_in_b,
                           const float* __restrict__ enc_out_w, const float* __restrict__ enc_out_b,
                           const float* __restrict__ sa_in_w, const float* __restrict__ sa_in_b,
                           const float* __restrict__ sa_out_w, const float* __restrict__ sa_out_b,
                           const float* __restrict__ ca_in_w, const float* __restrict__ ca_in_b,
                           const float* __restrict__ ca_out_w, const float* __restrict__ ca_out_b,
                           const float* __restrict__ ef1, const float* __restrict__ df1,
                           const float* __restrict__ ef2, const float* __restrict__ df2,
                           const float* __restrict__ g2w,
                           _Float16* __restrict__ apk, float* __restrict__ fb,
                           _Float16* __restrict__ apw2) {
    if (blockIdx.x < NGRP * CSR_NB) {  // ---- scatter part (8-wide MLP unroll) ----
        int g = blockIdx.x & (NGRP - 1);
        int bi = blockIdx.x >> 3;
        int lo = g * NODES_PER_GRP, hi = lo + NODES_PER_GRP;
        const int stride = CSR_NB * 256;
#define SLD(q) int ee##q = e + q * stride; int d##q = -1, s##q = 0; \
               if (ee##q < NE) { d##q = __builtin_nontemporal_load(ei + NE + ee##q); \
                                 s##q = __builtin_nontemporal_load(ei + ee##q); }
#define SAT(q) if (d##q >= lo && d##q < hi) { int p = atomicAdd(&cnt[d##q], 1); \
               if (p < SLOT) srcs[(size_t)d##q * SLOT + p] = s##q; }
        for (int e = bi * 256 + threadIdx.x; e < NE; e += 8 * stride) {
            SLD(0) SLD(1) SLD(2) SLD(3) SLD(4) SLD(5) SLD(6) SLD(7)
            SAT(0) SAT(1) SAT(2) SAT(3) SAT(4) SAT(5) SAT(6) SAT(7)
        }
        return;
    }
    // ---- prep part ----
    int gt = (blockIdx.x - NGRP * CSR_NB) * 256 + threadIdx.x;  // 640*256 = 163840 exact
    if (gt < 24576) {  // attention-fold A-frags + fused bias
        int tid = gt;
        int p = tid >> 12, rr = tid & 4095, j = rr >> 6, k = rr & 63;
        int li = p & 1;
        const float *iw, *ib, *ow, *ob;
        if (p < 2)      { iw = enc_in_w + li * 12288; ib = enc_in_b + li * 192; ow = enc_out_w + li * 4096; ob = enc_out_b + li * 64; }
        else if (p < 4) { iw = sa_in_w + li * 12288;  ib = sa_in_b + li * 192;  ow = sa_out_w + li * 4096;  ob = sa_out_b + li * 64; }
        else            { iw = ca_in_w + li * 12288;  ib = ca_in_b + li * 192;  ow = ca_out_w + li * 4096;  ob = ca_out_b + li * 64; }
        float a = 0.f;
        for (int m = 0; m < 64; m++) a = fmaf(ow[j * 64 + m], iw[(128 + m) * 64 + k], a);
        int l = ((k >> 3) & 1) * 32 + (j & 31);
        apk[p * 4096 + (((j >> 5) * 4 + (k >> 4)) * 64 + l) * 8 + (k & 7)] = (_Float16)a;
        if (k == 0) {
            float fa = ob[j];
            for (int m = 0; m < 64; m++) fa = fmaf(ow[j * 64 + m], ib[128 + m], fa);
            fb[p * 64 + j] = fa;
        }
    } else {  // FFN/gat2 packs
        int tid = gt - 24576;
        if (tid < 65536) {
            int pl = tid >> 14, idx = tid & 16383;
            int mt = idx >> 11, ks = (idx >> 9) & 3, l = (idx >> 3) & 63, d = idx & 7;
            int m = mt * 32 + (l & 31), k = ks * 16 + (l >> 5) * 8 + d;
            const float* f1 = (pl < 2) ? ef1 + pl * 16384 : df1 + (pl - 2) * 16384;
            apk[APK_F1 + pl * 16384 + idx] = (_Float16)f1[m * 64 + k];
        } else if (tid < 131072) {
            int rr = tid - 65536;
            int pl = rr >> 14, idx = rr & 16383;
            int mt = idx >> 13, ks = (idx >> 9) & 15, l = (idx >> 3) & 63, d = idx & 7;
            int m = mt * 32 + (l & 31), k = ks * 16 + (l >> 5) * 8 + d;
            const float* f2 = (pl < 2) ? ef2 + pl * 16384 : df2 + (pl - 2) * 16384;
            apk[APK_F2 + pl * 16384 + idx] = (_Float16)f2[m * 256 + k];
        } else {
            int rr = tid - 131072;
            int mtks = rr >> 9, l = (rr >> 3) & 63, d = rr & 7;
            int mt = mtks >> 3, ks = mtks & 7;
            int m = mt * 32 + (l & 31), k = ks * 16 + (l >> 5) * 8 + d;
            apw2[rr] = (_Float16)g2w[m * 128 + k];
        }
    }
}

// ---------- per-edge softmax weights, layer 1: 16 lanes per dst, fixed-slot ----------
// asp packed {as0, as2, as1, as3}; ad natural. ew[p] = {pack(w0,w2), pack(w1,w3)}
__global__ void k_ew1(const int* __restrict__ cnt, const int* __restrict__ srcs,
                      const float* __restrict__ asp, const float* __restrict__ ad_,
                      uint2* __restrict__ ew) {
    int t = blockIdx.x * 256 + threadIdx.x;
    int d = t >> 4, li = t & 15;
    if (d >= NN) return;
    size_t off = (size_t)d * SLOT;
    int deg = cnt[d]; if (deg > SLOT) deg = SLOT;
    float4 b = *(const float4*)(ad_ + d * 4);
    for (int j = li; j < deg; j += 16) {
        int s = srcs[off + j];
        float4 a = *(const float4*)(asp + s * 4);
        float e0 = a.x + b.x; e0 = fmaxf(e0, 0.2f * e0);
        float e2 = a.y + b.z; e2 = fmaxf(e2, 0.2f * e2);
        float e1 = a.z + b.y; e1 = fmaxf(e1, 0.2f * e1);
        float e3 = a.w + b.w; e3 = fmaxf(e3, 0.2f * e3);
        union { unsigned u; _Float16 h[2]; } c0, c1;
        c0.h[0] = (_Float16)__expf(e0); c0.h[1] = (_Float16)__expf(e2);
        c1.h[0] = (_Float16)__expf(e1); c1.h[1] = (_Float16)__expf(e3);
        uint2 o; o.x = c0.u; o.y = c1.u;
        ew[off + j] = o;
    }
}

// ---------- per-edge softmax weights, layer 2 (natural head order), fixed-slot ----------
__global__ void k_ew2(const int* __restrict__ cnt, const int* __restrict__ srcs,
                      const float* __restrict__ as_, const float* __restrict__ ad_,
                      uint2* __restrict__ ew) {
    int t = blockIdx.x * 256 + threadIdx.x;
    int d = t >> 4, li = t & 15;
    if (d >= NN) return;
    size_t off = (size_t)d * SLOT;
    int deg = cnt[d]; if (deg > SLOT) deg = SLOT;
    float4 b = *(const float4*)(ad_ + d * 4);
    for (int j = li; j < deg; j += 16) {
        int s = srcs[off + j];
        float4 a = *(const float4*)(as_ + s * 4);
        float e0 = a.x + b.x; e0 = fmaxf(e0, 0.2f * e0);
        float e1 = a.y + b.y; e1 = fmaxf(e1, 0.2f * e1);
        float e2 = a.z + b.z; e2 = fmaxf(e2, 0.2f * e2);
        float e3 = a.w + b.w; e3 = fmaxf(e3, 0.2f * e3);
        union { unsigned u; _Float16 h[2]; } c0, c1;
        c0.h[0] = (_Float16)__expf(e0); c0.h[1] = (_Float16)__expf(e1);
        c1.h[0] = (_Float16)__expf(e2); c1.h[1] = (_Float16)__expf(e3);
        uint2 o; o.x = c0.u; o.y = c1.u;
        ew[off + j] = o;
    }
}

// ---------- GAT layer 1: scalar-pipe srcs/ew, 8-wide NAMED-SCALAR gather unroll ----------
#define G1LD(q)  int s##q = sp[j + q]; uint2 e##q = wp[j + q];
#define G1LDM(q) int jj##q = j + q; int jc##q = jj##q < deg ? jj##q : deg - 1; \
                 int s##q = sp[jc##q]; uint2 e##q = wp[jc##q]; \
                 if (jj##q >= deg) { e##q.x = 0u; e##q.y = 0u; }
#define G1GA(q)  f16x2 p##q = *(const f16x2*)(h1p + (size_t)s##q * 128 + lane * 2);
#define G1AC(q, W0, W1, A0, A1) { \
    union { unsigned u; _Float16 h[2]; } c; c.u = hA ? e##q.y : e##q.x; \
    float w0 = (float)c.h[0], w1 = (float)c.h[1]; \
    W0 += w0; W1 += w1; \
    A0 = fmaf(w0, (float)p##q[0], A0); A1 = fmaf(w1, (float)p##q[1], A1); }

__global__ void k_gat1(const int* __restrict__ cnt, const int* __restrict__ srcs,
                       const uint2* __restrict__ ew, const _Float16* __restrict__ h1p,
                       const float* __restrict__ bias, _Float16* __restrict__ g1h) {
    int wid = __builtin_amdgcn_readfirstlane((blockIdx.x * 256 + threadIdx.x) >> 6);
    int lane = threadIdx.x & 63;
    if (wid >= NN) return;
    int deg = cnt[wid]; if (deg > SLOT) deg = SLOT;
    int hA = lane >> 5;
    const int* sp = srcs + (size_t)wid * SLOT;
    const uint2* wp = ew + (size_t)wid * SLOT;
    float ws0 = 0.f, ws1 = 0.f, ac0 = 0.f, ac1 = 0.f;
    float ws0b = 0.f, ws1b = 0.f, ac0b = 0.f, ac1b = 0.f;
    int j = 0;
    for (; j + 8 <= deg; j += 8) {
        G1LD(0) G1LD(1) G1LD(2) G1LD(3) G1LD(4) G1LD(5) G1LD(6) G1LD(7)
        G1GA(0) G1GA(1) G1GA(2) G1GA(3) G1GA(4) G1GA(5) G1GA(6) G1GA(7)
        G1AC(0, ws0, ws1, ac0, ac1)     G1AC(1, ws0b, ws1b, ac0b, ac1b)
        G1AC(2, ws0, ws1, ac0, ac1)     G1AC(3, ws0b, ws1b, ac0b, ac1b)
        G1AC(4, ws0, ws1, ac0, ac1)     G1AC(5, ws0b, ws1b, ac0b, ac1b)
        G1AC(6, ws0, ws1, ac0, ac1)     G1AC(7, ws0b, ws1b, ac0b, ac1b)
    }
    if (j < deg) {
        G1LDM(0) G1LDM(1) G1LDM(2) G1LDM(3) G1LDM(4) G1LDM(5) G1LDM(6) G1LDM(7)
        G1GA(0) G1GA(1) G1GA(2) G1GA(3) G1GA(4) G1GA(5) G1GA(6) G1GA(7)
        G1AC(0, ws0, ws1, ac0, ac1)     G1AC(1, ws0b, ws1b, ac0b, ac1b)
        G1AC(2, ws0, ws1, ac0, ac1)     G1AC(3, ws0b, ws1b, ac0b, ac1b)
        G1AC(4, ws0, ws1, ac0, ac1)     G1AC(5, ws0b, ws1b, ac0b, ac1b)
        G1AC(6, ws0, ws1, ac0, ac1)     G1AC(7, ws0b, ws1b, ac0b, ac1b)
    }
    ws0 += ws0b; ws1 += ws1b; ac0 += ac0b; ac1 += ac1b;
    float v0 = ac0 / ws0 + bias[lane];      v0 = fmaxf(v0, 0.01f * v0);
    float v1 = ac1 / ws1 + bias[lane + 64]; v1 = fmaxf(v1, 0.01f * v1);
    g1h[(size_t)wid * 128 + lane] = (_Float16)v0;
    g1h[(size_t)wid * 128 + lane + 64] = (_Float16)v1;
}

// ---------- GAT layer 2, fixed-slot ----------
#define G2LD(q)  int s##q = sp[j + q]; uint2 e##q = wp[j + q];
#define G2LDM(q) int jj##q = j + q; int jc##q = jj##q < deg ? jj##q : deg - 1; \
                 int s##q = sp[jc##q]; uint2 e##q = wp[jc##q]; \
                 if (jj##q >= deg) { e##q.x = 0u; e##q.y = 0u; }
#define G2GA(q)  float hv##q = (float)h2h[(size_t)s##q * 64 + lane];
#define G2AC(q, W, A) { \
    unsigned sel = (hd & 2) ? e##q.y : e##q.x; \
    union { unsigned u; _Float16 h[2]; } c; c.u = sel >> sh; \
    float w = (float)c.h[0]; W += w; A = fmaf(w, hv##q, A); }

__global__ void k_gat2(const int* __restrict__ cnt, const int* __restrict__ srcs,
                       const uint2* __restrict__ ew, const _Float16* __restrict__ h2h,
                       const float* __restrict__ bias, _Float16* __restrict__ g2h) {
    int wid = __builtin_amdgcn_readfirstlane((blockIdx.x * 256 + threadIdx.x) >> 6);
    int lane = threadIdx.x & 63;
    if (wid >= NN) return;
    int deg = cnt[wid]; if (deg > SLOT) deg = SLOT;
    int hd = lane >> 4;
    int sh = (hd & 1) * 16;
    const int* sp = srcs + (size_t)wid * SLOT;
    const uint2* wp = ew + (size_t)wid * SLOT;
    float ws = 0.f, ac = 0.f, wsb = 0.f, acb = 0.f;
    int j = 0;
    for (; j + 8 <= deg; j += 8) {
        G2LD(0) G2LD(1) G2LD(2) G2LD(3) G2LD(4) G2LD(5) G2LD(6) G2LD(7)
        G2GA(0) G2GA(1) G2GA(2) G2GA(3) G2GA(4) G2GA(5) G2GA(6) G2GA(7)
        G2AC(0, ws, ac)  G2AC(1, wsb, acb)
        G2AC(2, ws, ac)  G2AC(3, wsb, acb)
        G2AC(4, ws, ac)  G2AC(5, wsb, acb)
        G2AC(6, ws, ac)  G2AC(7, wsb, acb)
    }
    if (j < deg) {
        G2LDM(0) G2LDM(1) G2LDM(2) G2LDM(3) G2LDM(4) G2LDM(5) G2LDM(6) G2LDM(7)
        G2GA(0) G2GA(1) G2GA(2) G2GA(3) G2GA(4) G2GA(5) G2GA(6) G2GA(7)
        G2AC(0, ws, ac)  G2AC(1, wsb, acb)
        G2AC(2, ws, ac)  G2AC(3, wsb, acb)
        G2AC(4, ws, ac)  G2AC(5, wsb, acb)
        G2AC(6, ws, ac)  G2AC(7, wsb, acb)
    }
    ws += wsb; ac += acb;
    float v = ac / ws + bias[lane]; v = fmaxf(v, 0.01f * v);
    g2h[(size_t)wid * 64 + lane] = (_Float16)v;
}

// ---------- h2 = g1h @ gat2_w.T via MFMA + fused att2 coeffs ----------
#define GROW 136
#define CROW 72
__global__ __launch_bounds__(256, 2) void k_h2m(const _Float16* __restrict__ g1h,
                                                const _Float16* __restrict__ apw2,
                                                const float* __restrict__ asw,
                                                const float* __restrict__ adw,
                                                _Float16* __restrict__ h2h,
                                                float* __restrict__ as_,
                                                float* __restrict__ ad_) {
    __shared__ _Float16 ls[4 * 32 * GROW];
    const int t = threadIdx.x;
    const int w = t >> 6, l = t & 63;
    const int col = l & 31, hf = l >> 5;
    const int wv = blockIdx.x * 4 + w;
    const int nb = wv * 32;
    if (nb >= NN) return;
    _Float16* g16 = ls + w * (32 * GROW);
    const int r = l >> 1, hb = l & 1;
    {
        int nr = nb + r; if (nr >= NN) nr = NN - 1;
        const _Float16* src = g1h + (size_t)nr * 128 + hb * 64;
        _Float16* dst = g16 + r * GROW + hb * 64;
#pragma unroll
        for (int q = 0; q < 8; q++)
            *(f16x8*)(dst + q * 8) = *(const f16x8*)(src + q * 8);
    }
    f16x8 bf[8];
#pragma unroll
    for (int ks = 0; ks < 8; ks++)
        bf[ks] = *(const f16x8*)(g16 + col * GROW + ks * 16 + hf * 8);
    f32x16 acc0, acc1;
#pragma unroll
    for (int i = 0; i < 16; i++) { acc0[i] = 0.f; acc1[i] = 0.f; }
#pragma unroll
    for (int ks = 0; ks < 8; ks++) {
        f16x8 a0 = *(const f16x8*)(apw2 + ((0 * 8 + ks) * 64 + l) * 8);
        f16x8 a1 = *(const f16x8*)(apw2 + ((1 * 8 + ks) * 64 + l) * 8);
        acc0 = __builtin_amdgcn_mfma_f32_32x32x16_f16(a0, bf[ks], acc0, 0, 0, 0);
        acc1 = __builtin_amdgcn_mfma_f32_32x32x16_f16(a1, bf[ks], acc1, 0, 0, 0);
    }
    // fused att2: per-head dots on f16-rounded values (identical to reading h2h back)
    {
        float pa0 = 0.f, pa1 = 0.f, pa2 = 0.f, pa3 = 0.f;
        float pd0 = 0.f, pd1 = 0.f, pd2 = 0.f, pd3 = 0.f;
#pragma unroll
        for (int rg = 0; rg < 4; rg++)
#pragma unroll
            for (int i = 0; i < 4; i++) {
                int rr = rg * 4 + i;
                int f = i + rg * 8 + hf * 4;      // feature row in [0,32)
                float h0v = (float)(_Float16)acc0[rr];
                float h1v = (float)(_Float16)acc1[rr];
                float s0 = asw[f], d0v = adw[f];
                float s1 = asw[32 + f], d1v = adw[32 + f];
                if (rg < 2) { pa0 = fmaf(h0v, s0, pa0); pd0 = fmaf(h0v, d0v, pd0);
                              pa2 = fmaf(h1v, s1, pa2); pd2 = fmaf(h1v, d1v, pd2); }
                else        { pa1 = fmaf(h0v, s0, pa1); pd1 = fmaf(h0v, d0v, pd1);
                              pa3 = fmaf(h1v, s1, pa3); pd3 = fmaf(h1v, d1v, pd3); }
            }
        pa0 += __shfl_xor(pa0, 32, 64); pa1 += __shfl_xor(pa1, 32, 64);
        pa2 += __shfl_xor(pa2, 32, 64); pa3 += __shfl_xor(pa3, 32, 64);
        pd0 += __shfl_xor(pd0, 32, 64); pd1 += __shfl_xor(pd1, 32, 64);
        pd2 += __shfl_xor(pd2, 32, 64); pd3 += __shfl_xor(pd3, 32, 64);
        if (hf == 0 && nb + col < NN) {
            *(float4*)(as_ + (size_t)(nb + col) * 4) = make_float4(pa0, pa1, pa2, pa3);
            *(float4*)(ad_ + (size_t)(nb + col) * 4) = make_float4(pd0, pd1, pd2, pd3);
        }
    }
    _Float16* c16 = g16;
#pragma unroll
    for (int rg = 0; rg < 4; rg++) {
        f16x4 h0, h1;
#pragma unroll
        for (int i = 0; i < 4; i++) { h0[i] = (_Float16)acc0[rg * 4 + i]; h1[i] = (_Float16)acc1[rg * 4 + i]; }
        *(f16x4*)(c16 + col * CROW + rg * 8 + hf * 4) = h0;
        *(f16x4*)(c16 + col * CROW + 32 + rg * 8 + hf * 4) = h1;
    }
    if (nb + r < NN) {
        _Float16* dst = h2h + (size_t)(nb + r) * 64 + hb * 32;
        const _Float16* srow = c16 + r * CROW + hb * 32;
#pragma unroll
        for (int q = 0; q < 4; q++)
            *(f16x8*)(dst + q * 8) = *(const f16x8*)(srow + q * 8);
    }
}

// ---------- MFMA transformer: round-3 shape (4x64 waves, 2-barrier LDS staging) ----------
struct XQ {
    const _Float16* apk; const float* fb;
    const float* ef1b; const float* ef2b; const float* df1b; const float* df2b;
    const float* el1g; const float* el1b; const float* el2g; const float* el2b;
    const float* dl1g; const float* dl1b; const float* dl2g; const float* dl2b;
    const float* dl3g; const float* dl3b;
};

__device__ __forceinline__ void xstore(_Float16* xw, const float y[4][16], int col, int hf) {
#pragma unroll
    for (int nt = 0; nt < 2; nt++)
#pragma unroll
        for (int mt = 0; mt < 2; mt++)
#pragma unroll
            for (int rg = 0; rg < 4; rg++) {
                f16x4 h4;
#pragma unroll
                for (int i = 0; i < 4; i++) h4[i] = (_Float16)y[mt * 2 + nt][rg * 4 + i];
                *(f16x4*)(xw + (nt * 32 + col) * XROW + mt * 32 + rg * 8 + hf * 4) = h4;
            }
}

__device__ __forceinline__ void loadbf(const _Float16* xw, f16x8 bf[2][4], int col, int hf) {
#pragma unroll
    for (int nt = 0; nt < 2; nt++)
#pragma unroll
        for (int ks = 0; ks < 4; ks++)
            bf[nt][ks] = *(const f16x8*)(xw + (nt * 32 + col) * XROW + ks * 16 + hf * 8);
}

__device__ __forceinline__ void lnw(float y[4][16], const float* g, const float* b, int hf) {
#pragma unroll
    for (int nt = 0; nt < 2; nt++) {
        float s = 0.f, q = 0.f;
#pragma unroll
        for (int mt = 0; mt < 2; mt++)
#pragma unroll
            for (int r = 0; r < 16; r++) { float v = y[mt * 2 + nt][r]; s += v; q = fmaf(v, v, q); }
        s += __shfl_xor(s, 32, 64);
        q += __shfl_xor(q, 32, 64);
        float m = s * 0.015625f;
        float var = fmaf(q, 0.015625f, -m * m);
        float rs = rsqrtf(var + 1e-5f);
#pragma unroll
        for (int mt = 0; mt < 2; mt++)
#pragma unroll
            for (int rg = 0; rg < 4; rg++) {
                float4 g4 = *(const float4*)(g + mt * 32 + rg * 8 + hf * 4);
                float4 b4 = *(const float4*)(b + mt * 32 + rg * 8 + hf * 4);
                float* yp = &y[mt * 2 + nt][rg * 4];
                yp[0] = fmaf((yp[0] - m) * rs, g4.x, b4.x);
                yp[1] = fmaf((yp[1] - m) * rs, g4.y, b4.y);
                yp[2] = fmaf((yp[2] - m) * rs, g4.z, b4.z);
                yp[3] = fmaf((yp[3] - m) * rs, g4.w, b4.w);
            }
    }
}

__global__ __launch_bounds__(256, 2) void k_xform(const _Float16* __restrict__ yin,
                                                  float* __restrict__ yout, XQ P) {
    __shared__ _Float16 xs[4 * 64 * XROW];
    __shared__ _Float16 wb[8192];
    const int t = threadIdx.x;
    const int w = t >> 6, l = t & 63;
    const int col = l & 31, hf = l >> 5;
    _Float16* xw = xs + w * (64 * XROW);
    const int nb = blockIdx.x * 256 + w * 64;
    const int nn0 = nb + col, nn1 = nb + 32 + col;
    const int nc0 = nn0 < NN ? nn0 : NN - 1;
    const int nc1 = nn1 < NN ? nn1 : NN - 1;

    float y[4][16];
#pragma unroll
    for (int mt = 0; mt < 2; mt++)
#pragma unroll
        for (int nt = 0; nt < 2; nt++) {
            const _Float16* src = yin + (size_t)(nt ? nc1 : nc0) * 64 + mt * 32 + hf * 4;
#pragma unroll
            for (int rg = 0; rg < 4; rg++) {
                f16x4 v = *(const f16x4*)(src + rg * 8);
#pragma unroll
                for (int i = 0; i < 4; i++) y[mt * 2 + nt][rg * 4 + i] = (float)v[i];
            }
        }
    f16x8 bf[2][4];
    xstore(xw, y, col, hf);
    loadbf(xw, bf, col, hf);

#pragma unroll 1
    for (int layer = 0; layer < 4; layer++) {
        const bool enc = layer < 2;
        const int li = enc ? layer : layer - 2;
        const int nat = enc ? 1 : 2;
#pragma unroll 1
        for (int at = 0; at < nat; at++) {
            const int p = enc ? layer : (at == 0 ? 2 + li : 4 + li);
            const _Float16* apA = P.apk + p * 4096;
            __syncthreads();
#pragma unroll
            for (int i = 0; i < 2; i++)
                *(f16x8*)(wb + (t + i * 256) * 8) = *(const f16x8*)(apA + (t + i * 256) * 8);
            __syncthreads();
            const float* fbp = P.fb + p * 64;
            f32x16 acc[4];
#pragma unroll
            for (int mt = 0; mt < 2; mt++) {
                f32x16 a;
#pragma unroll
                for (int rg = 0; rg < 4; rg++) {
                    float4 b4 = *(const float4*)(fbp + mt * 32 + rg * 8 + hf * 4);
                    a[rg * 4 + 0] = b4.x; a[rg * 4 + 1] = b4.y; a[rg * 4 + 2] = b4.z; a[rg * 4 + 3] = b4.w;
                }
                acc[mt * 2 + 0] = a; acc[mt * 2 + 1] = a;
            }
#pragma unroll
            for (int mt = 0; mt < 2; mt++)
#pragma unroll
                for (int ks = 0; ks < 4; ks++) {
                    f16x8 af = *(const f16x8*)(wb + ((mt * 4 + ks) * 64 + l) * 8);
                    acc[mt * 2 + 0] = __builtin_amdgcn_mfma_f32_32x32x16_f16(af, bf[0][ks], acc[mt * 2 + 0], 0, 0, 0);
                    acc[mt * 2 + 1] = __builtin_amdgcn_mfma_f32_32x32x16_f16(af, bf[1][ks], acc[mt * 2 + 1], 0, 0, 0);
                }
#pragma unroll
            for (int ti = 0; ti < 4; ti++)
#pragma unroll
                for (int r = 0; r < 16; r++) y[ti][r] += acc[ti][r];
            const float *g, *b;
            if (enc)          { g = P.el1g + li * 64; b = P.el1b + li * 64; }
            else if (at == 0) { g = P.dl1g + li * 64; b = P.dl1b + li * 64; }
            else              { g = P.dl2g + li * 64; b = P.dl2b + li * 64; }
            lnw(y, g, b, hf);
            xstore(xw, y, col, hf);
            loadbf(xw, bf, col, hf);
        }
        const int pl = enc ? layer : 2 + li;
        const _Float16* apF1 = P.apk + APK_F1 + pl * 16384;
        const _Float16* apF2 = P.apk + APK_F2 + pl * 16384;
        const float* f1bp = (enc ? P.ef1b : P.df1b) + li * 256;
        const float* f2bp = (enc ? P.ef2b : P.df2b) + li * 64;
        f32x16 out[4];
#pragma unroll
        for (int mt = 0; mt < 2; mt++) {
            f32x16 a;
#pragma unroll
            for (int rg = 0; rg < 4; rg++) {
                float4 b4 = *(const float4*)(f2bp + mt * 32 + rg * 8 + hf * 4);
                a[rg * 4 + 0] = b4.x; a[rg * 4 + 1] = b4.y; a[rg * 4 + 2] = b4.z; a[rg * 4 + 3] = b4.w;
            }
            out[mt * 2 + 0] = a; out[mt * 2 + 1] = a;
        }
#pragma unroll 1
        for (int c = 0; c < 4; c++) {
            __syncthreads();
#pragma unroll
            for (int i = 0; i < 2; i++)
                *(f16x8*)(wb + (t + i * 256) * 8) = *(const f16x8*)(apF1 + c * 4096 + (t + i * 256) * 8);
            *(f16x8*)(wb + 4096 + t * 8) = *(const f16x8*)(apF2 + c * 2048 + t * 8);
            *(f16x8*)(wb + 6144 + t * 8) = *(const f16x8*)(apF2 + 8192 + c * 2048 + t * 8);
            __syncthreads();
            f32x16 ha[4];
#pragma unroll
            for (int hmt = 0; hmt < 2; hmt++) {
                f32x16 a;
#pragma unroll
                for (int rg = 0; rg < 4; rg++) {
                    float4 b4 = *(const float4*)(f1bp + c * 64 + hmt * 32 + rg * 8 + hf * 4);
                    a[rg * 4 + 0] = b4.x; a[rg * 4 + 1] = b4.y; a[rg * 4 + 2] = b4.z; a[rg * 4 + 3] = b4.w;
                }
                ha[hmt * 2 + 0] = a; ha[hmt * 2 + 1] = a;
            }
#pragma unroll
            for (int hmt = 0; hmt < 2; hmt++)
#pragma unroll
                for (int ks = 0; ks < 4; ks++) {
                    f16x8 af = *(const f16x8*)(wb + ((hmt * 4 + ks) * 64 + l) * 8);
                    ha[hmt * 2 + 0] = __builtin_amdgcn_mfma_f32_32x32x16_f16(af, bf[0][ks], ha[hmt * 2 + 0], 0, 0, 0);
                    ha[hmt * 2 + 1] = __builtin_amdgcn_mfma_f32_32x32x16_f16(af, bf[1][ks], ha[hmt * 2 + 1], 0, 0, 0);
                }
#pragma unroll
            for (int nt = 0; nt < 2; nt++)
#pragma unroll
                for (int hmt = 0; hmt < 2; hmt++)
#pragma unroll
                    for (int rg = 0; rg < 4; rg++) {
                        f16x4 h4;
#pragma unroll
                        for (int i = 0; i < 4; i++)
                            h4[i] = (_Float16)fmaxf(ha[hmt * 2 + nt][rg * 4 + i], 0.f);
                        *(f16x4*)(xw + (nt * 32 + col) * XROW + hmt * 32 + rg * 8 + hf * 4) = h4;
                    }
#pragma unroll
            for (int ksl = 0; ksl < 4; ksl++) {
                f16x8 hbf0 = *(const f16x8*)(xw + col * XROW + ksl * 16 + hf * 8);
                f16x8 hbf1 = *(const f16x8*)(xw + (32 + col) * XROW + ksl * 16 + hf * 8);
#pragma unroll
                for (int mt = 0; mt < 2; mt++) {
                    f16x8 af = *(const f16x8*)(wb + 4096 + mt * 2048 + (ksl * 64 + l) * 8);
                    out[mt * 2 + 0] = __builtin_amdgcn_mfma_f32_32x32x16_f16(af, hbf0, out[mt * 2 + 0], 0, 0, 0);
                    out[mt * 2 + 1] = __builtin_amdgcn_mfma_f32_32x32x16_f16(af, hbf1, out[mt * 2 + 1], 0, 0, 0);
                }
            }
        }
#pragma unroll
        for (int ti = 0; ti < 4; ti++)
#pragma unroll
            for (int r = 0; r < 16; r++) y[ti][r] += out[ti][r];
        const float* g2 = (enc ? P.el2g : P.dl3g) + li * 64;
        const float* b2 = (enc ? P.el2b : P.dl3b) + li * 64;
        lnw(y, g2, b2, hf);
        if (layer < 3) {
            xstore(xw, y, col, hf);
            loadbf(xw, bf, col, hf);
        }
    }
#pragma unroll
    for (int mt = 0; mt < 2; mt++)
#pragma unroll
        for (int nt = 0; nt < 2; nt++) {
            int n = nt ? nn1 : nn0;
            if (n < NN) {
                float* dst = yout + (size_t)n * 64 + mt * 32 + hf * 4;
#pragma unroll
                for (int rg = 0; rg < 4; rg++) {
                    const float* yp = &y[mt * 2 + nt][rg * 4];
                    *(float4*)(dst + rg * 8) = make_float4(yp[0], yp[1], yp[2], yp[3]);
                }
            }
        }
}

// ---------- global mean pool + fused final fc ----------
__global__ void k_pool(const float* __restrict__ y, const int* __restrict__ batch,
                       const float* __restrict__ fcw, const float* __restrict__ fcb,
                       float* __restrict__ out) {
    int b = blockIdx.x;
    int t = threadIdx.x;
    int ch = t & 63, r = t >> 6;
    int lo = 0, hi = NN;
    while (lo < hi) { int mid = (lo + hi) >> 1; if (batch[mid] < b) lo = mid + 1; else hi = mid; }
    int st = lo;
    hi = NN;
    while (lo < hi) { int mid = (lo + hi) >> 1; if (batch[mid] < b + 1) lo = mid + 1; else hi = mid; }
    int en = lo;
    float s = 0.f;
    for (int i = st + r; i < en; i += 4) s += y[(size_t)i * 64 + ch];
    __shared__ float red[256];
    __shared__ float pl[64];
    red[t] = s;
    __syncthreads();
    if (t < 64) {
        float tot = red[t] + red[t + 64] + red[t + 128] + red[t + 192];
        int cnt = en - st; if (cnt < 1) cnt = 1;
        pl[t] = tot / (float)cnt;
    }
    __syncthreads();
    if (t < 33) {
        const float* wv = fcw + t * 64;
        float a0 = 0.f, a1 = 0.f, a2 = 0.f, a3 = 0.f;
#pragma unroll
        for (int k = 0; k < 16; k++) {
            a0 = fmaf(pl[4 * k], wv[4 * k], a0);
            a1 = fmaf(pl[4 * k + 1], wv[4 * k + 1], a1);
            a2 = fmaf(pl[4 * k + 2], wv[4 * k + 2], a2);
            a3 = fmaf(pl[4 * k + 3], wv[4 * k + 3], a3);
        }
        out[b * 33 + t] = fcb[t] + (a0 + a1) + (a2 + a3);
    }
}

extern "C" void kernel_launch(void* const* d_in, const int* in_sizes, int n_in,
                              void* d_out, int out_size, void* d_ws, size_t ws_size,
                              hipStream_t stream) {
    (void)in_sizes; (void)n_in; (void)out_size; (void)ws_size;
    char* ws = (char*)d_ws;
    size_t o = 0;
    auto A = [&](size_t b) { size_t r = o; o += (b + 255) & ~(size_t)255; return r; };
    _Float16* h1p = (_Float16*)(ws + A((size_t)NN * 128 * 2));
    _Float16* h2h = (_Float16*)(ws + A((size_t)NN * 64 * 2));
    _Float16* g1h = (_Float16*)(ws + A((size_t)NN * 128 * 2));
    _Float16* g2h = (_Float16*)(ws + A((size_t)NN * 64 * 2));
    float* f_y   = (float*)(ws + A((size_t)NN * 64 * 4));
    float* f_asp = (float*)(ws + A((size_t)NN * 4 * 4));
    float* f_ad1 = (float*)(ws + A((size_t)NN * 4 * 4));
    float* f_as2 = (float*)(ws + A((size_t)NN * 4 * 4));
    float* f_ad2 = (float*)(ws + A((size_t)NN * 4 * 4));
    int* i_cnt   = (int*)(ws + A((size_t)NN * 4));
    int* i_srcs  = (int*)(ws + A((size_t)NN * SLOT * 4));
    uint2* e_w   = (uint2*)(ws + A((size_t)NN * SLOT * 8));
    float* f_fb  = (float*)(ws + A((size_t)6 * 64 * 4));
    _Float16* f_apk = (_Float16*)(ws + A((size_t)APK_TOT * 2));
    _Float16* apw2  = (_Float16*)(ws + A((size_t)8192 * 2));

    const float* x   = (const float*)d_in[0];
    const int* ei    = (const int*)d_in[1];
    const int* batch = (const int*)d_in[2];
    #define F32(i) ((const float*)d_in[i])

    k_h1<<<NN * 64 / 256, 256, 0, stream>>>(x, F32(3), F32(4), F32(5), F32(6), F32(7),
                                            h1p, f_asp, f_ad1, i_cnt, i_srcs);
    k_scatprep<<<NGRP * CSR_NB + 640, 256, 0, stream>>>(
        ei, i_cnt, i_srcs,
        F32(13), F32(14), F32(15), F32(16),
        F32(25), F32(26), F32(27), F32(28),
        F32(29), F32(30), F32(31), F32(32),
        F32(17), F32(33), F32(19), F32(35), F32(9),
        f_apk, f_fb, apw2);
    k_ew1<<<NN * 16 / 256, 256, 0, stream>>>(i_cnt, i_srcs, f_asp, f_ad1, e_w);
    k_gat1<<<NN * 64 / 256, 256, 0, stream>>>(i_cnt, i_srcs, e_w, h1p, F32(8), g1h);
    k_h2m<<<(NN / 32 + 3) / 4, 256, 0, stream>>>(g1h, apw2, F32(10), F32(11), h2h, f_as2, f_ad2);
    k_ew2<<<NN * 16 / 256, 256, 0, stream>>>(i_cnt, i_srcs, f_as2, f_ad2, e_w);
    k_gat2<<<NN * 64 / 256, 256, 0, stream>>>(i_cnt, i_srcs, e_w, h2h, F32(12), g2h);
    XQ Q;
    Q.apk = f_apk; Q.fb = f_fb;
    Q.ef1b = F32(18); Q.ef2b = F32(20);
    Q.df1b = F32(34); Q.df2b = F32(36);
    Q.el1g = F32(21); Q.el1b = F32(22); Q.el2g = F32(23); Q.el2b = F32(24);
    Q.dl1g = F32(37); Q.dl1b = F32(38); Q.dl2g = F32(39); Q.dl2b = F32(40);
    Q.dl3g = F32(41); Q.dl3b = F32(42);
    k_xform<<<(NN + 255) / 256, 256, 0, stream>>>(g2h, f_y, Q);
    k_pool<<<NG, 256, 0, stream>>>(f_y, batch, F32(43), F32(44), (float*)d_out);
    #undef F32
}